// Round 4
// baseline (456.268 us; speedup 1.0000x reference)
//
#include <hip/hip_runtime.h>

// CSTR gated-estimator trajectory cost — 2 lanes/sample, 2 samples/thread.
// Regime (R1-R3): latency-bound at ~190 cyc/step regardless of instruction
// count (40/30/27 instr per step all measured the same). The wave has one
// dependency chain and ~130 idle issue-cycles per step. Fix: interleave TWO
// independent samples per lane-pair so each sample's chain stalls are filled
// by the other sample's instructions. k=2 chosen so issue (~120 cyc/step-pair)
// stays at/below the exposed chain; k=3 would become issue-bound.
//
// Step math identical to R3 (verified): RK4 collapsed analytically, phi in
// exp2 domain, u via delta-independent dot products, hkxh carried.

#define T_STEPS 2048
#define BATCH   8192

__device__ __forceinline__ float swapf(float v) {
    // quad_perm [1,0,3,2]: swap adjacent lane pairs.
    return __int_as_float(__builtin_amdgcn_update_dpp(
        0, __float_as_int(v), 0xB1, 0xF, 0xF, true));
}

struct St {
    float x, xh, hkxh, accO, accU, accD;
};

__global__ __launch_bounds__(64, 1) void cstr_kernel(
    const float* __restrict__ w,   // (B, 2, T)
    const float* __restrict__ K,   // (1, 2)
    const float* __restrict__ L,   // (4, 4)
    const float* __restrict__ M,   // (1, 4)
    const float* __restrict__ Mo,  // (1, 1)
    float* __restrict__ out)       // (B,)
{
    const int lane = threadIdx.x;
    const int p = lane & 1;                          // owned state index
    const int j = lane >> 1;                         // slot in wave [0,32)
    const int sA = blockIdx.x * 64 + j;              // sample A
    const int sB = sA + 32;                          // sample B

    // ---- uniform scalars ----
    const float k1c = K[0], k2c = K[1];
    const float s11 = L[0];
    const float s12 = L[1] + L[4];
    const float s13 = L[2] + L[8];
    const float s14 = L[3] + L[12];
    const float s22 = L[5];
    const float s23 = L[6] + L[9];
    const float s24 = L[7] + L[13];
    const float s33 = L[10];
    const float s34 = L[11] + L[14];
    const float s44 = L[15];
    const float m1 = M[0], m2 = M[1], m3 = M[2], m4 = M[3];
    const float c0 = Mo[0];

    constexpr float Hs = 0.01f;
    constexpr float Ad = 1.0f - 2.0f * Hs;           // 0.98
    constexpr float RU = 0.1f / (Hs * Hs);           // R / H^2 = 1000
    constexpr float SC = -1.44269504088896340736f;   // -log2(e)

    // ---- per-lane phi coefficients (lane-split quadratic form) ----
    float P1, P2, P3, P4, P5, P6, P7, P8;
    if (p == 0) { P1 = s11; P2 = s12; P3 = s13; P4 = s14; P5 = m1; P6 = s33; P7 = s34; P8 = m3; }
    else        { P1 = s22; P2 = 0.f; P3 = s24; P4 = s23; P5 = m2; P6 = s44; P7 = 0.f; P8 = m4; }
    P1 *= SC; P2 *= SC; P3 *= SC; P4 *= SC; P5 *= SC; P6 *= SC; P7 *= SC; P8 *= SC;
    const float P9 = 0.5f * c0 * SC;

    const float hk   = Hs * (p ? k2c : k1c);          // Hs * K_own
    const float Cown = p ? (-Hs * Hs) : (0.5f * Hs * Hs);

    // ---- two independent per-thread states ----
    St A, B;
    A.x = p ? 0.0f : 1.0f;  A.xh = A.x;  A.hkxh = Hs * k1c;
    A.accO = 0.0f; A.accU = 0.0f; A.accD = 0.0f;
    B = A;

    auto step = [&](St& S, float wv, bool first, bool cost) {
        float xo  = swapf(S.x);
        float xho = swapf(S.xh);
        // delta-independent work
        float hkx_h = hk * S.x;
        float hkx   = hkx_h + swapf(hkx_h);            // Hs * K·x
        float base  = fmaf(Ad, S.x, fmaf(Hs, xo, wv + Cown));
        float dxh   = S.x - S.xh;
        float dk    = hkx - S.hkxh;
        if (cost) {
            S.accO = fmaf(S.x, S.x, S.accO);
            S.accU = fmaf(hkx, hkx, S.accU);
        }
        // gate chain: phi -> exp2 -> rcp
        float d;
        if (first) {
            d = 1.0f;
        } else {
            float t  = fmaf(P2, xo, fmaf(P1, S.x, P5));
            t        = fmaf(P3, S.xh, t);
            t        = fmaf(P4, xho, t);
            float u2 = fmaf(P7, xho, fmaf(P6, S.xh, P8));
            float part = fmaf(S.x, t, fmaf(S.xh, u2, P9));
            float e  = __builtin_amdgcn_exp2f(part + swapf(part)); // exp(-phi)
            d        = __builtin_amdgcn_rcpf(1.0f + e);
        }
        if (cost) S.accD += d;
        // short post-delta tail
        S.xh = fmaf(d, dxh, S.xh);
        float hu = fmaf(d, dk, S.hkxh);   // Hs * K·xh_new
        S.hkxh = hu;
        S.x = base + hu;
    };

    // 16 steps for both samples, interleaved per step
    auto chunk2 = [&](const float4* bA, const float4* bB, bool first, bool lastchunk) {
        #pragma unroll
        for (int q = 0; q < 4; ++q) {
            float4 a = bA[q], b = bB[q];
            bool f = first && (q == 0);
            step(A, a.x, f, true);  step(B, b.x, f, true);
            step(A, a.y, false, true);  step(B, b.y, false, true);
            step(A, a.z, false, true);  step(B, b.z, false, true);
            bool c = !(lastchunk && (q == 3));   // t=T-1: no stage cost
            step(A, a.w, false, c);  step(B, b.w, false, c);
        }
    };

    // own-row streams: T floats = 512 float4 = 128 chunks of 16 steps
    const float4* rA = reinterpret_cast<const float4*>(w + ((size_t)sA * 2 + p) * T_STEPS);
    const float4* rB = reinterpret_cast<const float4*>(w + ((size_t)sB * 2 + p) * T_STEPS);

    float4 XA[4], YA[4], XB[4], YB[4];
    #pragma unroll
    for (int q = 0; q < 4; ++q) { XA[q] = rA[q];     XB[q] = rB[q]; }      // chunk 0
    #pragma unroll
    for (int q = 0; q < 4; ++q) { YA[q] = rA[4 + q]; YB[q] = rB[4 + q]; }  // chunk 1

    chunk2(XA, XB, true, false);                       // chunk 0 (step 0 special)

    for (int i = 0; i < 63; ++i) {                     // chunks 1..126
        const float4* pa = rA + (size_t)(2 + 2 * i) * 4;
        const float4* pb = rB + (size_t)(2 + 2 * i) * 4;
        #pragma unroll
        for (int q = 0; q < 4; ++q) { XA[q] = pa[q]; XB[q] = pb[q]; }   // prefetch 2+2i
        chunk2(YA, YB, false, false);                  // process 1+2i
        const float4* qa = rA + (size_t)(3 + 2 * i) * 4;
        const float4* qb = rB + (size_t)(3 + 2 * i) * 4;
        #pragma unroll
        for (int q = 0; q < 4; ++q) { YA[q] = qa[q]; YB[q] = qb[q]; }   // prefetch 3+2i
        chunk2(XA, XB, false, false);                  // process 2+2i
    }
    chunk2(YA, YB, false, true);                       // chunk 127 (t=T-1: no cost)

    // terminal cost 10*(x1^2+x2^2), split by ownership; unscale control cost
    A.accO = fmaf(10.0f * A.x, A.x, A.accO);
    B.accO = fmaf(10.0f * B.x, B.x, B.accO);
    float JA = A.accO + swapf(A.accO) + fmaf(RU, A.accU, A.accD);
    float JB = B.accO + swapf(B.accO) + fmaf(RU, B.accU, B.accD);
    if (p == 0) { out[sA] = JA; out[sB] = JB; }
}

extern "C" void kernel_launch(void* const* d_in, const int* in_sizes, int n_in,
                              void* d_out, int out_size, void* d_ws, size_t ws_size,
                              hipStream_t stream) {
    const float* w  = (const float*)d_in[0];
    const float* K  = (const float*)d_in[1];
    const float* L  = (const float*)d_in[2];
    const float* M  = (const float*)d_in[3];
    const float* Mo = (const float*)d_in[4];
    float* out = (float*)d_out;

    // 8192 samples / (64 samples per wave) = 128 blocks of 64 threads
    hipLaunchKernelGGL(cstr_kernel, dim3(BATCH / 64), dim3(64), 0, stream,
                       w, K, L, M, Mo, out);
}

// Round 5
// 355.138 us; speedup vs baseline: 1.2848x; 1.2848x over previous
//
#include <hip/hip_runtime.h>

// CSTR gated-estimator trajectory cost — polynomial sigmoid, 1 thread/sample.
//
// Model (fitted to R1-R4): time/step = max(critical chain, issue); all samples
// already parallel, so wave count / occupancy are irrelevant. R1-R3 measured
// ~190 cyc/step with issue 115-160 => chain-bound, and the chain decomposes as
// ~60 cyc dependent VALU + ~130 cyc of v_exp + v_rcp dependent latency on the
// loop-carried cycle (phi -> exp -> rcp -> delta -> x -> phi). The trans
// latency IS the floor; no scheduling can hide it.
//
// Fix: replace sigmoid's exp+rcp with a pure-VALU degree-9 odd polynomial:
//   delta = 0.5 + u*P(u^2),  u = clamp(phi/2, +-1.6)
// P = Newton interpolation of tanh(u)/u at u = {0,.4,.8,1.2,1.6}; max error
// <= ~1.5e-4 over the clamp range (checked at phi=0.6,1,2,3.2). |phi| <~ 0.7
// in practice (0.05-scale weights, |z|<~1.4), so the clamp never binds.
// Error budget: 2047 * 1.5e-4 ~ 0.3 on J, vs threshold headroom ~12.
//
// New chain ~58 cyc; issue ~85-95 cyc -> issue-bound (first time).
// Kept from R3: RK4 collapsed analytically, carried hkxh = Hs*K.xh,
// delta-independent base/dxh/dk, cost in Hs-scaled domain.

#define T_STEPS 2048
#define BATCH   8192

__global__ __launch_bounds__(64, 1) void cstr_kernel(
    const float* __restrict__ w,   // (B, 2, T)
    const float* __restrict__ K,   // (1, 2)
    const float* __restrict__ L,   // (4, 4)
    const float* __restrict__ M,   // (1, 4)
    const float* __restrict__ Mo,  // (1, 1)
    float* __restrict__ out)       // (B,)
{
    const int b = blockIdx.x * 64 + threadIdx.x;

    // ---- uniform constants ----
    const float k1c = K[0], k2c = K[1];
    // symmetrized AND pre-halved quadratic coefficients: u = phi/2 directly
    const float q11 = 0.5f * L[0];
    const float q12 = 0.5f * (L[1] + L[4]);
    const float q13 = 0.5f * (L[2] + L[8]);
    const float q14 = 0.5f * (L[3] + L[12]);
    const float q22 = 0.5f * L[5];
    const float q23 = 0.5f * (L[6] + L[9]);
    const float q24 = 0.5f * (L[7] + L[13]);
    const float q33 = 0.5f * L[10];
    const float q34 = 0.5f * (L[11] + L[14]);
    const float q44 = 0.5f * L[15];
    const float qm1 = 0.5f * M[0], qm2 = 0.5f * M[1];
    const float qm3 = 0.5f * M[2], qm4 = 0.5f * M[3];
    const float qc  = 0.5f * Mo[0];

    constexpr float Hs = 0.01f;
    constexpr float Ad = 1.0f - 2.0f * Hs;   // 0.98
    constexpr float C1 = 0.5f * Hs * Hs;
    constexpr float C2 = -Hs * Hs;
    constexpr float RU = 0.1f / (Hs * Hs);   // R / H^2 = 1000
    // 0.5*tanh(u)/u interpolation coefficients (in s = u^2):
    constexpr float PC0 = 0.5f;
    constexpr float PC1 = -0.16628205f;
    constexpr float PC2 = 0.06307510f;
    constexpr float PC3 = -0.01837280f;
    constexpr float PC4 = 0.00252805f;

    const float hk1 = Hs * k1c, hk2 = Hs * k2c;

    // ---- state ----
    float x1 = 1.0f, x2 = 0.0f, xh1 = 1.0f, xh2 = 0.0f;
    float hkxh = hk1;              // Hs * K.xh0  (xh0 = (1,0))
    float accO = 0.0f;             // sum x1^2 + x2^2
    float accU = 0.0f;             // sum (Hs*K.x)^2
    float accD = 0.0f;             // sum delta

    auto step = [&](float w1, float w2, bool first, bool cost) {
        // ---- delta-independent work (off-chain) ----
        float hkx   = fmaf(hk1, x1, hk2 * x2);            // Hs * K.x
        float base1 = fmaf(Ad, x1, fmaf(Hs, x2, w1 + C1));
        float base2 = fmaf(Hs, x1, fmaf(Ad, x2, w2 + C2));
        float dxh1  = x1 - xh1;
        float dxh2  = x2 - xh2;
        float dk    = hkx - hkxh;
        if (cost) {
            accO = fmaf(x1, x1, accO);
            accO = fmaf(x2, x2, accO);
            accU = fmaf(hkx, hkx, accU);
        }
        // ---- gate: u = phi/2, delta = 0.5 + u*P(u^2)  (pure VALU) ----
        float d;
        if (first) {
            d = 1.0f;              // i==0: gate forced open
        } else {
            float a1 = fmaf(q13, xh1, fmaf(q12, x2, fmaf(q11, x1, qm1)));
            a1 = fmaf(q14, xh2, a1);
            float a2 = fmaf(q24, xh2, fmaf(q23, xh1, fmaf(q22, x2, qm2)));
            float a3 = fmaf(q34, xh2, fmaf(q33, xh1, qm3));
            float a4 = fmaf(q44, xh2, qm4);
            float u = fmaf(x1, a1, fmaf(x2, a2, fmaf(xh1, a3, fmaf(xh2, a4, qc))));
            u = fminf(1.6f, fmaxf(-1.6f, u));             // v_med3 clamp
            float s  = u * u;
            float pp = fmaf(s, fmaf(s, fmaf(s, fmaf(s, PC4, PC3), PC2), PC1), PC0);
            d = fmaf(u, pp, 0.5f);
        }
        if (cost) accD += d;
        // ---- short post-delta tail ----
        xh1 = fmaf(d, dxh1, xh1);
        xh2 = fmaf(d, dxh2, xh2);
        float hu = fmaf(d, dk, hkxh);   // Hs * K.xh_new
        hkxh = hu;
        x1 = base1 + hu;
        x2 = base2 + hu;
    };

    // own rows: row1 = w[b][0][:], row2 = w[b][1][:], each 512 float4 groups
    const float4* r1p = reinterpret_cast<const float4*>(w + (size_t)b * (2 * T_STEPS));
    const float4* r2p = r1p + (T_STEPS / 4);

    {   // group 0: step 0 is gate-forced
        float4 a = r1p[0], c = r2p[0];
        step(a.x, c.x, true,  true);
        step(a.y, c.y, false, true);
        step(a.z, c.z, false, true);
        step(a.w, c.w, false, true);
    }
    #pragma unroll 2
    for (int g = 1; g < 511; ++g) {     // clean middle: no flags
        float4 a = r1p[g], c = r2p[g];
        step(a.x, c.x, false, true);
        step(a.y, c.y, false, true);
        step(a.z, c.z, false, true);
        step(a.w, c.w, false, true);
    }
    {   // group 511: t = 2047 excluded from stage cost
        float4 a = r1p[511], c = r2p[511];
        step(a.x, c.x, false, true);
        step(a.y, c.y, false, true);
        step(a.z, c.z, false, true);
        step(a.w, c.w, false, false);
    }

    // terminal cost 10*(x1^2+x2^2); unscale control cost
    float J = accO + fmaf(RU, accU, accD);
    out[b] = fmaf(10.0f, fmaf(x1, x1, x2 * x2), J);
}

extern "C" void kernel_launch(void* const* d_in, const int* in_sizes, int n_in,
                              void* d_out, int out_size, void* d_ws, size_t ws_size,
                              hipStream_t stream) {
    const float* w  = (const float*)d_in[0];
    const float* K  = (const float*)d_in[1];
    const float* L  = (const float*)d_in[2];
    const float* M  = (const float*)d_in[3];
    const float* Mo = (const float*)d_in[4];
    float* out = (float*)d_out;

    hipLaunchKernelGGL(cstr_kernel, dim3(BATCH / 64), dim3(64), 0, stream,
                       w, K, L, M, Mo, out);
}